// Round 1
// 202.511 us; speedup vs baseline: 1.0156x; 1.0156x over previous
//
#include <hip/hip_runtime.h>
#include <math.h>

#define BB 4
#define CC 256
#define NN 4096
#define DQ 32
#define LOG2E 1.44269504f

typedef _Float16 half8 __attribute__((ext_vector_type(8)));
typedef _Float16 half4 __attribute__((ext_vector_type(4)));
typedef float float4v __attribute__((ext_vector_type(4)));

// ---------------- prep: W -> f16 (log2e folded into Wq/bq) ----------------
// Wh[320][256] f16: rows 0-31 Wq*log2e, 32-63 Wk, 64-319 Wv. bh[320] f32.
__global__ __launch_bounds__(64) void prep_kernel(
    const float* __restrict__ Wq, const float* __restrict__ bq,
    const float* __restrict__ Wk, const float* __restrict__ bk,
    const float* __restrict__ Wv, const float* __restrict__ bv,
    _Float16* __restrict__ Wh, float* __restrict__ bh)
{
    int o = blockIdx.x, t = threadIdx.x;
    const float* src; float scale = 1.0f, bias;
    if (o < DQ)            { src = Wq + o * CC;        scale = LOG2E; bias = bq[o] * LOG2E; }
    else if (o < 2 * DQ)   { src = Wk + (o - DQ) * CC;                bias = bk[o - DQ]; }
    else                   { src = Wv + (o - 2 * DQ) * CC;            bias = bv[o - 2 * DQ]; }
    float4 v = *(const float4*)(src + t * 4);
    half4 h = { (_Float16)(v.x * scale), (_Float16)(v.y * scale),
                (_Float16)(v.z * scale), (_Float16)(v.w * scale) };
    *(half4*)(Wh + o * CC + t * 4) = h;
    if (t == 0) bh[o] = bias;
}

// ---------------- proj: MFMA GEMM, all 320 outputs x 32-pixel tile ----------------
// n-tile halved to 32 (grid 512 = 2 blocks/CU; was 256 = 1/CU, latency-bound).
__global__ __launch_bounds__(256) void proj_kernel(
    const float* __restrict__ x, const _Float16* __restrict__ Wh,
    const float* __restrict__ bh,
    _Float16* __restrict__ Qt, _Float16* __restrict__ Kt,
    _Float16* __restrict__ Vh)
{
    __shared__ _Float16 xl[32 * 256];     // [n][c], chunk-of-8 XOR swizzle: chunk' = (c>>3) ^ n
    __shared__ _Float16 os_qk[32 * 72];   // [n][o<64 + pad]
    __shared__ _Float16 os_v[256 * 40];   // [c][n + pad]

    const int tid = threadIdx.x;
    const int lane = tid & 63, w = tid >> 6;
    const int i16 = lane & 15, q = lane >> 4;
    const int n0 = blockIdx.x * 32, b = blockIdx.y;

    // stage x tile transposed to f16 [n][c] with swizzle
    const float* xb = x + (size_t)b * CC * NN + n0;
    #pragma unroll
    for (int u = 0; u < 8; ++u) {
        int idx = u * 256 + tid;
        int c = idx >> 3, n4 = idx & 7;
        float4 v = *(const float4*)(xb + (size_t)c * NN + n4 * 4);
        int chunk = c >> 3, cl = c & 7;
        float vv[4] = {v.x, v.y, v.z, v.w};
        #pragma unroll
        for (int e = 0; e < 4; ++e) {
            int n = n4 * 4 + e;
            xl[n * 256 + ((chunk ^ n) * 8) + cl] = (_Float16)vv[e];
        }
    }

    // bias init (C-layout: reg r <-> row o offset r)
    float4v acc[5][2];
    const int obase = 80 * w;
    #pragma unroll
    for (int ot = 0; ot < 5; ++ot) {
        float4 b4 = *(const float4*)(bh + obase + 16 * ot + 4 * q);
        #pragma unroll
        for (int nt = 0; nt < 2; ++nt)
            acc[ot][nt] = (float4v){b4.x, b4.y, b4.z, b4.w};
    }
    __syncthreads();

    // K loop: 8 steps of 32 channels
    #pragma unroll
    for (int k = 0; k < 8; ++k) {
        half8 af[5], bf[2];
        #pragma unroll
        for (int ot = 0; ot < 5; ++ot)
            af[ot] = *(const half8*)(Wh + (size_t)(obase + 16 * ot + i16) * CC + k * 32 + 8 * q);
        #pragma unroll
        for (int nt = 0; nt < 2; ++nt) {
            int n = 16 * nt + i16;
            bf[nt] = *(const half8*)&xl[n * 256 + (((4 * k + q) ^ n) * 8)];
        }
        #pragma unroll
        for (int ot = 0; ot < 5; ++ot)
            #pragma unroll
            for (int nt = 0; nt < 2; ++nt)
                acc[ot][nt] = __builtin_amdgcn_mfma_f32_16x16x32_f16(af[ot], bf[nt], acc[ot][nt], 0, 0, 0);
    }

    // epilogue: write D into transpose buffers
    #pragma unroll
    for (int ot = 0; ot < 5; ++ot) {
        int og = obase + 16 * ot;
        #pragma unroll
        for (int nt = 0; nt < 2; ++nt) {
            int n = 16 * nt + i16;
            if (og < 64) {   // Q/K rows: pack 4 consecutive o into b64
                half4 hv = { (_Float16)acc[ot][nt][0], (_Float16)acc[ot][nt][1],
                             (_Float16)acc[ot][nt][2], (_Float16)acc[ot][nt][3] };
                *(half4*)&os_qk[n * 72 + og + 4 * q] = hv;
            } else {         // V rows: scattered b16 into [c][n]
                int cb = og - 64 + 4 * q;
                #pragma unroll
                for (int r = 0; r < 4; ++r)
                    os_v[(cb + r) * 40 + n] = (_Float16)acc[ot][nt][r];
            }
        }
    }
    __syncthreads();

    // coalesced global stores
    _Float16* Qtb = Qt + (size_t)b * NN * DQ;
    _Float16* Ktb = Kt + (size_t)b * NN * DQ;
    {
        int n = tid >> 3, p = tid & 7;
        half8 hv = *(const half8*)&os_qk[n * 72 + 8 * p];
        if (p < 4) *(half8*)(Qtb + (size_t)(n0 + n) * DQ + 8 * p) = hv;
        else       *(half8*)(Ktb + (size_t)(n0 + n) * DQ + 8 * (p - 4)) = hv;
    }
    _Float16* Vb = Vh + (size_t)b * CC * NN;
    #pragma unroll
    for (int u = 0; u < 4; ++u) {
        int c = u * 64 + (tid >> 2), p = tid & 3;
        half8 hv = *(const half8*)&os_v[c * 40 + 8 * p];
        *(half8*)(Vb + (size_t)c * NN + n0 + 8 * p) = hv;
    }
}

// ---------------- rowstat: exact per-query (m2, l) of S2 = K.Q^T ----------------
// 4-way key split (grid 1024 = 4 blocks/CU) + reg double-buffer of the K tile.
// M2/L: [b][4][N] f32.
__global__ __launch_bounds__(256) void rowstat_kernel(
    const _Float16* __restrict__ Qt, const _Float16* __restrict__ Kt,
    float* __restrict__ M2, float* __restrict__ L)
{
    __shared__ _Float16 k_lds[64 * 32];
    const int tid = threadIdx.x;
    const int lane = tid & 63, w = tid >> 6;
    const int i16 = lane & 15, q = lane >> 4;
    const int q0 = blockIdx.x * 64, js = blockIdx.y, b = blockIdx.z;

    const _Float16* Qtb = Qt + (size_t)b * NN * DQ;
    const _Float16* Ktb = Kt + (size_t)b * NN * DQ;
    half8 qb = *(const half8*)(Qtb + (size_t)(q0 + 16 * w + i16) * DQ + 8 * q);

    const int jb = js * 1024;
    const int jl = tid >> 2, dg = tid & 3;
    half8 kv = *(const half8*)(Ktb + (size_t)(jb + jl) * DQ + 8 * dg);

    float m = -INFINITY, l = 0.f;
    for (int t = 0; t < 16; ++t) {
        __syncthreads();
        *(half8*)&k_lds[jl * 32 + ((dg ^ (jl & 3)) * 8)] = kv;
        __syncthreads();
        if (t < 15)     // prefetch next tile; latency hides under MFMA+VALU below
            kv = *(const half8*)(Ktb + (size_t)(jb + (t + 1) * 64 + jl) * DQ + 8 * dg);
        float4v s[4];
        __builtin_amdgcn_s_setprio(1);
        #pragma unroll
        for (int jt = 0; jt < 4; ++jt) {
            int j = 16 * jt + i16;
            half8 ka = *(const half8*)&k_lds[j * 32 + ((q ^ (j & 3)) * 8)];
            float4v z = {0.f, 0.f, 0.f, 0.f};
            s[jt] = __builtin_amdgcn_mfma_f32_16x16x32_f16(ka, qb, z, 0, 0, 0);
        }
        __builtin_amdgcn_s_setprio(0);
        float tmax = s[0][0];
        #pragma unroll
        for (int jt = 0; jt < 4; ++jt)
            #pragma unroll
            for (int r = 0; r < 4; ++r)
                tmax = fmaxf(tmax, s[jt][r]);
        float mnew = fmaxf(m, tmax);
        float sum = 0.f;
        #pragma unroll
        for (int jt = 0; jt < 4; ++jt)
            #pragma unroll
            for (int r = 0; r < 4; ++r)
                sum += exp2f(s[jt][r] - mnew);
        l = l * exp2f(m - mnew) + sum;
        m = mnew;
    }
    // combine the 4 quads (same query, different key rows)
    #pragma unroll
    for (int off = 16; off <= 32; off <<= 1) {
        float mo = __shfl_xor(m, off, 64);
        float lo = __shfl_xor(l, off, 64);
        float mn = fmaxf(m, mo);
        l = l * exp2f(m - mn) + lo * exp2f(mo - mn);
        m = mn;
    }
    if (q == 0) {
        int qi = q0 + 16 * w + i16;
        M2[((size_t)b * 4 + js) * NN + qi] = m;
        L[((size_t)b * 4 + js) * NN + qi] = l;
    }
}

// ---------------- attn: single-pass, precomputed (m2, 1/l) ----------------
// Channel-split 2-way: block owns 128 of 256 channels (grid 1024 = 4 blocks/CU,
// LDS 24.5 KB). Next K/V tile prefetched to regs after barrier B; LDS-written
// after next barrier A (global latency hides under S+exp+PV).
__global__ __launch_bounds__(256) void attn_kernel(
    const float* __restrict__ x,
    const _Float16* __restrict__ Qt, const _Float16* __restrict__ Kt,
    const _Float16* __restrict__ Vh,
    const float* __restrict__ M2, const float* __restrict__ L,
    float* __restrict__ out)
{
    __shared__ _Float16 k_lds[64 * 32];    // [j][d], d-chunk ^= (j&3)
    __shared__ _Float16 v_lds[128 * 64];   // [c][j], j-chunk ^= (c&7)
    __shared__ _Float16 ps[32 * 72];       // shared P: [i][j + pad]

    const int tid = threadIdx.x;
    const int w = tid >> 6, lane = tid & 63;
    const int i16 = lane & 15, q = lane >> 4;
    const int i0 = blockIdx.x * 32, cs = blockIdx.y, b = blockIdx.z;
    const int c0 = cs * 128;

    const _Float16* Ktb = Kt + (size_t)b * NN * DQ;
    const _Float16* Vb  = Vh + (size_t)b * CC * NN + (size_t)c0 * NN;

    // combine the 4 j-quarters of (m,l); per-lane for its 2 queries
    float m2v[2], linv[2];
    #pragma unroll
    for (int it = 0; it < 2; ++it) {
        int qi = i0 + 16 * it + i16;
        float mm = -INFINITY, ll = 0.f;
        #pragma unroll
        for (int p = 0; p < 4; ++p) {
            float mp = M2[((size_t)b * 4 + p) * NN + qi];
            float lp = L [((size_t)b * 4 + p) * NN + qi];
            float mn = fmaxf(mm, mp);
            ll = ll * exp2f(mm - mn) + lp * exp2f(mp - mn);
            mm = mn;
        }
        m2v[it] = mm;
        linv[it] = 1.0f / ll;
    }

    half8 qb[2];
    {
        const _Float16* Qtb = Qt + (size_t)b * NN * DQ;
        qb[0] = *(const half8*)(Qtb + (size_t)(i0 + i16) * DQ + 8 * q);
        qb[1] = *(const half8*)(Qtb + (size_t)(i0 + 16 + i16) * DQ + 8 * q);
    }

    float4v O[2][2];
    #pragma unroll
    for (int ct = 0; ct < 2; ++ct)
        #pragma unroll
        for (int it = 0; it < 2; ++it)
            O[ct][it] = (float4v){0.f, 0.f, 0.f, 0.f};

    const int jK = tid >> 2, dgK = tid & 3;      // K staging: 1 half8/thread
    const int cbV = tid >> 3, jgV = tid & 7;     // V staging: 4 half8/thread

    half8 kv, vv[4];
    kv = *(const half8*)(Ktb + (size_t)jK * DQ + 8 * dgK);
    #pragma unroll
    for (int u = 0; u < 4; ++u)
        vv[u] = *(const half8*)(Vb + (size_t)(u * 32 + cbV) * NN + 8 * jgV);

    for (int j0 = 0; j0 < NN; j0 += 64) {
        __syncthreads();   // A: prior PV reads + prior ps done
        *(half8*)&k_lds[jK * 32 + ((dgK ^ (jK & 3)) * 8)] = kv;
        #pragma unroll
        for (int u = 0; u < 4; ++u) {
            int c = u * 32 + cbV;
            *(half8*)&v_lds[c * 64 + ((jgV ^ (c & 7)) * 8)] = vv[u];
        }
        __syncthreads();   // B: tiles staged

        // prefetch next tile into regs (no wait until next iter's LDS write)
        if (j0 + 64 < NN) {
            kv = *(const half8*)(Ktb + (size_t)(j0 + 64 + jK) * DQ + 8 * dgK);
            #pragma unroll
            for (int u = 0; u < 4; ++u)
                vv[u] = *(const half8*)(Vb + (size_t)(u * 32 + cbV) * NN + (j0 + 64) + 8 * jgV);
        }

        // S^T strip for this wave: keys [j0+16w, j0+16w+16)
        {
            int j = 16 * w + i16;
            half8 ka = *(const half8*)&k_lds[j * 32 + ((q ^ (j & 3)) * 8)];
            #pragma unroll
            for (int it = 0; it < 2; ++it) {
                float4v z = {0.f, 0.f, 0.f, 0.f};
                float4v s = __builtin_amdgcn_mfma_f32_16x16x32_f16(ka, qb[it], z, 0, 0, 0);
                half4 hv = { (_Float16)exp2f(s[0] - m2v[it]),
                             (_Float16)exp2f(s[1] - m2v[it]),
                             (_Float16)exp2f(s[2] - m2v[it]),
                             (_Float16)exp2f(s[3] - m2v[it]) };
                *(half4*)&ps[(16 * it + i16) * 72 + 16 * w + 4 * q] = hv;
            }
        }
        __syncthreads();   // C: P ready

        half8 pb[2][2];
        #pragma unroll
        for (int ks = 0; ks < 2; ++ks)
            #pragma unroll
            for (int it = 0; it < 2; ++it)
                pb[ks][it] = *(const half8*)&ps[(16 * it + i16) * 72 + 32 * ks + 8 * q];
        __builtin_amdgcn_s_setprio(1);
        #pragma unroll
        for (int ct = 0; ct < 2; ++ct) {
            int c = 32 * w + 16 * ct + i16;
            #pragma unroll
            for (int ks = 0; ks < 2; ++ks) {
                int g = 4 * ks + q;
                half8 va = *(const half8*)&v_lds[c * 64 + ((g ^ (c & 7)) * 8)];
                #pragma unroll
                for (int it = 0; it < 2; ++it)
                    O[ct][it] = __builtin_amdgcn_mfma_f32_16x16x32_f16(va, pb[ks][it], O[ct][it], 0, 0, 0);
            }
        }
        __builtin_amdgcn_s_setprio(0);
    }

    // epilogue: O * (1/l) + residual
    const float* xb = x + (size_t)b * CC * NN;
    float* ob = out + (size_t)b * CC * NN;
    #pragma unroll
    for (int ct = 0; ct < 2; ++ct)
        #pragma unroll
        for (int it = 0; it < 2; ++it)
            #pragma unroll
            for (int r = 0; r < 4; ++r) {
                int c = c0 + 32 * w + 16 * ct + 4 * q + r;
                size_t idx = (size_t)c * NN + i0 + 16 * it + i16;
                ob[idx] = xb[idx] + O[ct][it][r] * linv[it];
            }
}

extern "C" void kernel_launch(void* const* d_in, const int* in_sizes, int n_in,
                              void* d_out, int out_size, void* d_ws, size_t ws_size,
                              hipStream_t stream) {
    const float* x  = (const float*)d_in[0];
    const float* Wq = (const float*)d_in[1];
    const float* bq = (const float*)d_in[2];
    const float* Wk = (const float*)d_in[3];
    const float* bk = (const float*)d_in[4];
    const float* Wv = (const float*)d_in[5];
    const float* bv = (const float*)d_in[6];
    float* out = (float*)d_out;

    char* ws = (char*)d_ws;
    _Float16* Wh = (_Float16*)(ws);                 // 320*256*2 = 163840
    float*    bh = (float*)(ws + 163840);           // 1280
    _Float16* Qt = (_Float16*)(ws + 262144);        // 4*4096*32*2 = 1 MB
    _Float16* Kt = (_Float16*)(ws + 1310720);       // 1 MB
    _Float16* Vh = (_Float16*)(ws + 2359296);       // 4*256*4096*2 = 8 MB
    float*    M2 = (float*)(ws + 10747904);         // 4*4*4096*4 = 256 KB
    float*    L  = (float*)(ws + 11010048);         // 256 KB

    prep_kernel<<<dim3(320), 64, 0, stream>>>(Wq, bq, Wk, bk, Wv, bv, Wh, bh);
    proj_kernel<<<dim3(NN / 32, BB), 256, 0, stream>>>(x, Wh, bh, Qt, Kt, Vh);
    rowstat_kernel<<<dim3(NN / 64, 4, BB), 256, 0, stream>>>(Qt, Kt, M2, L);
    attn_kernel<<<dim3(NN / 32, 2, BB), 256, 0, stream>>>(x, Qt, Kt, Vh, M2, L, out);
}